// Round 14
// baseline (245.473 us; speedup 1.0000x reference)
//
#include <hip/hip_runtime.h>
#include <hip/hip_bf16.h>
#include <stdint.h>

#define NEG_INF -100000000.0f

typedef __attribute__((ext_vector_type(8))) short bf16x8;
typedef __attribute__((ext_vector_type(4))) float f32x4;
typedef __attribute__((ext_vector_type(4))) int i32x4;

// lgkm-only barrier: does NOT drain in-flight global (NT) stores/loads.
#define LGKM_BAR()                                                \
    do {                                                          \
        asm volatile("s_waitcnt lgkmcnt(0)" ::: "memory");        \
        __builtin_amdgcn_s_barrier();                             \
        __builtin_amdgcn_sched_barrier(0);                        \
    } while (0)

static __device__ __forceinline__ short f2bf(float x) {
    unsigned u = __float_as_uint(x);
    u = u + 0x7FFFu + ((u >> 16) & 1u);
    return (short)(u >> 16);
}

// ---------------- kernel 1: transpose + bf16-convert weights ----------------
__global__ void wtrans_kernel(const float* __restrict__ wq, const float* __restrict__ wk,
                              short* __restrict__ wtq, short* __restrict__ wtk) {
    __shared__ float tile[32][33];
    const float* w = blockIdx.z ? wk : wq;
    short* wt = blockIdx.z ? wtk : wtq;
    float scale = blockIdx.z ? 1.0f : 0.0625f;   // 1/sqrt(256) folded into wq
    int tx = threadIdx.x, ty = threadIdx.y;
    int c0 = blockIdx.x * 32;
    int k0 = blockIdx.y * 32;
#pragma unroll
    for (int i = 0; i < 4; i++)
        tile[ty + i * 8][tx] = w[(k0 + ty + i * 8) * 256 + c0 + tx];
    __syncthreads();
#pragma unroll
    for (int i = 0; i < 4; i++)
        wt[(c0 + ty + i * 8) * 256 + k0 + tx] = f2bf(tile[tx][ty + i * 8] * scale);
}

// ---------------- kernel 2: projection GEMM (pipelined) + (y==2) fragment-layout mask pack ----------------
// y=0: Q, y=1: K -> fragment layout [b][dc 8][row 1024][ks 32] bf16
// y=2: pack mask into MFMA-fragment-layout bit words:
//   word for (tile, m, w_o, lane_o), bit (r*8+n) = mask[tile*32+m*16+(lane_o>>4)*4+r][w_o*128+n*16+(lane_o&15)]
__global__ __launch_bounds__(512, 4)
void proj_kernel(const float* __restrict__ qin, const float* __restrict__ kin,
                 const short* __restrict__ wtq, const short* __restrict__ wtk,
                 short* __restrict__ Qb, short* __restrict__ Kb,
                 const int* __restrict__ mask, unsigned* __restrict__ pmask) {
    __shared__ __align__(16) char slds[40960];     // staging bufs / C-dump / mask-word overlay

    if (blockIdx.y == 2) {
        unsigned* words = (unsigned*)slds;         // [64 row][33]
        int t = threadIdx.x;
        int row = t >> 3, seg8 = t & 7;
        size_t grow = (size_t)blockIdx.x * 64 + row;
        const int* mrow = mask + grow * 1024;
#pragma unroll
        for (int jj = 0; jj < 4; jj++) {
            int j = seg8 + jj * 8;
            unsigned v = 0;
#pragma unroll
            for (int i = 0; i < 8; i++) {
                i32x4 x = __builtin_nontemporal_load(
                    reinterpret_cast<const i32x4*>(mrow + j * 4 + i * 128));
                unsigned nib = (unsigned)(x.x | (x.y << 1) | (x.z << 2) | (x.w << 3));
                v |= nib << (i * 4);
            }
            words[row * 33 + j] = v;
        }
        __syncthreads();
        int w_o = t >> 6, lane_o = t & 63;
        int g_o = lane_o >> 4, l15 = lane_o & 15;
        int bitpos = w_o * 4 + (l15 & 3);
        int jb = l15 >> 2;
        unsigned* obase = pmask + (size_t)blockIdx.x * 2048;   // 2 tiles * 1024 words
#pragma unroll
        for (int tt = 0; tt < 2; tt++)
#pragma unroll
            for (int mm = 0; mm < 2; mm++) {
                unsigned v = 0;
#pragma unroll
                for (int r = 0; r < 4; r++) {
                    int rrow = tt * 32 + mm * 16 + g_o * 4 + r;
#pragma unroll
                    for (int n = 0; n < 8; n++) {
                        unsigned bit = (words[rrow * 33 + n * 4 + jb] >> bitpos) & 1u;
                        v |= bit << (r * 8 + n);
                    }
                }
                obase[tt * 1024 + mm * 512 + t] = v;
            }
        return;
    }

    const float* x  = blockIdx.y ? kin : qin;
    const short* wt = blockIdx.y ? wtk : wtq;
    short* outp     = blockIdx.y ? Kb  : Qb;

    short* xl0 = (short*)slds;          // [64 row][32 k]
    short* wl0 = xl0 + 2048;            // [256 c][32 k]
    short* xl1 = (short*)(slds + 20480);
    short* wl1 = xl1 + 2048;

    int t = threadIdx.x;
    int lane = t & 63, w = t >> 6;
    int l15 = lane & 15, g = lane >> 4;
    int rowbase = blockIdx.x * 64;

    int srow = t >> 3, sseg = t & 7;
    const float* xrow = x + (size_t)(rowbase + srow) * 256 + sseg * 4;
    int wc0 = t >> 2, wseg0 = t & 3;
    int wc1 = (512 + t) >> 2, wseg1 = t & 3;

    f32x4 zero = {0.f, 0.f, 0.f, 0.f};
    f32x4 acc[4][2];
#pragma unroll
    for (int m = 0; m < 4; m++)
#pragma unroll
        for (int n = 0; n < 2; n++) acc[m][n] = zero;

    {
        f32x4 xv = __builtin_nontemporal_load(reinterpret_cast<const f32x4*>(xrow));
        int4 wv0 = *reinterpret_cast<const int4*>(wt + wc0 * 256 + wseg0 * 8);
        int4 wv1 = *reinterpret_cast<const int4*>(wt + wc1 * 256 + wseg1 * 8);
        short4 bb; bb.x = f2bf(xv.x); bb.y = f2bf(xv.y); bb.z = f2bf(xv.z); bb.w = f2bf(xv.w);
        *reinterpret_cast<short4*>(&xl0[srow * 32 + sseg * 4]) = bb;
        *reinterpret_cast<int4*>(&wl0[(size_t)t * 8]) = wv0;
        *reinterpret_cast<int4*>(&wl0[((size_t)512 + t) * 8]) = wv1;
    }
    LGKM_BAR();

#pragma unroll
    for (int dc = 0; dc < 8; dc++) {
        short* xc   = (dc & 1) ? xl1 : xl0;
        short* wcur = (dc & 1) ? wl1 : wl0;
        short* xn   = (dc & 1) ? xl0 : xl1;
        short* wn   = (dc & 1) ? wl0 : wl1;

        f32x4 xv; int4 wv0, wv1;
        if (dc < 7) {
            xv  = __builtin_nontemporal_load(reinterpret_cast<const f32x4*>(xrow + (dc + 1) * 32));
            wv0 = *reinterpret_cast<const int4*>(wt + wc0 * 256 + (dc + 1) * 32 + wseg0 * 8);
            wv1 = *reinterpret_cast<const int4*>(wt + wc1 * 256 + (dc + 1) * 32 + wseg1 * 8);
        }

        bf16x8 a[4], bfr[2];
#pragma unroll
        for (int m = 0; m < 4; m++)
            a[m] = *reinterpret_cast<const bf16x8*>(&xc[(m * 16 + l15) * 32 + g * 8]);
#pragma unroll
        for (int n = 0; n < 2; n++) {
            int c = w * 32 + n * 16 + l15;
            bfr[n] = *reinterpret_cast<const bf16x8*>(&wcur[c * 32 + g * 8]);
        }
#pragma unroll
        for (int m = 0; m < 4; m++)
#pragma unroll
            for (int n = 0; n < 2; n++)
                acc[m][n] = __builtin_amdgcn_mfma_f32_16x16x32_bf16(a[m], bfr[n], acc[m][n], 0, 0, 0);

        if (dc < 7) {
            short4 bb; bb.x = f2bf(xv.x); bb.y = f2bf(xv.y); bb.z = f2bf(xv.z); bb.w = f2bf(xv.w);
            *reinterpret_cast<short4*>(&xn[srow * 32 + sseg * 4]) = bb;
            *reinterpret_cast<int4*>(&wn[(size_t)t * 8]) = wv0;
            *reinterpret_cast<int4*>(&wn[((size_t)512 + t) * 8]) = wv1;
            LGKM_BAR();
        }
    }

    LGKM_BAR();
    short* sdump = (short*)slds;    // [64 row][296]
#pragma unroll
    for (int m = 0; m < 4; m++)
#pragma unroll
        for (int n = 0; n < 2; n++) {
            int col = w * 32 + n * 16 + l15;
#pragma unroll
            for (int r = 0; r < 4; r++)
                sdump[(m * 16 + g * 4 + r) * 296 + col] = f2bf(acc[m][n][r]);
        }
    LGKM_BAR();

    int b8 = rowbase >> 10;
    int rloc = rowbase & 1023;
#pragma unroll
    for (int o = 0; o < 4; o++) {
        int gu = o * 512 + t;
        int dc = gu >> 8;
        int rem = gu & 255;
        int row = rem >> 2, kseg = rem & 3;
        int4 v = *reinterpret_cast<const int4*>(&sdump[row * 296 + dc * 32 + kseg * 8]);
        size_t idx = (((size_t)b8 * 8 + dc) * 1024 + rloc + row) * 32 + kseg * 8;
        *reinterpret_cast<int4*>(outp + idx) = v;
    }
}

// ---------------- kernel 3: fused QK^T + tanh-clip + mask + log_softmax ----------------
// R13 in-register pass-1 + SINGLE 16-row park (33KB -> 4 blocks/CU, 32 waves/CU)
// + s_setprio(1) around the MFMA cluster. 3 lgkm-only barriers; NT stores fly.
__global__ __launch_bounds__(512, 4)
void attn_kernel(const short* __restrict__ Qs, const short* __restrict__ Ks,
                 const unsigned* __restrict__ pmf, float* __restrict__ out) {
    const int RSB = 1034;                              // shorts/row: <=2-way banks
    __shared__ __align__(16) short park[16 * RSB];     // 33,088 B (one half at a time)
    __shared__ float redbuf[32 * 8];                   // [row 0..31][wave] partial sums

    int t = threadIdx.x;
    int lane = t & 63, w = t >> 6;
    int l15 = lane & 15, g = lane >> 4;

    int bid = blockIdx.x;
    int wg = (bid & 7) * 256 + (bid >> 3);   // XCD swizzle
    int b = wg >> 5;
    int qt = wg & 31;
    int brow = qt * 32;

    // fragment-layout packed mask: 2 words/thread, prefetched behind QK^T
    const unsigned* pm = pmf + (size_t)(b * 32 + qt) * 1024;
    unsigned mw0 = pm[t];
    unsigned mw1 = pm[512 + t];

    const short* qb = Qs + (size_t)b * 8 * 32768;
    const short* kb = Ks + (size_t)b * 8 * 32768;

    f32x4 zero = {0.f, 0.f, 0.f, 0.f};
    f32x4 acc[2][8];
#pragma unroll
    for (int m = 0; m < 2; m++)
#pragma unroll
        for (int n = 0; n < 8; n++) acc[m][n] = zero;

    for (int dc = 0; dc < 8; dc++) {
        const short* qc = qb + dc * 32768;
        const short* kc = kb + dc * 32768;
        bf16x8 a0 = *reinterpret_cast<const bf16x8*>(qc + (brow + l15) * 32 + g * 8);
        bf16x8 a1 = *reinterpret_cast<const bf16x8*>(qc + (brow + 16 + l15) * 32 + g * 8);
        __builtin_amdgcn_s_setprio(1);
#pragma unroll
        for (int n = 0; n < 8; n++) {
            bf16x8 bf = *reinterpret_cast<const bf16x8*>(kc + (w * 128 + n * 16 + l15) * 32 + g * 8);
            acc[0][n] = __builtin_amdgcn_mfma_f32_16x16x32_bf16(a0, bf, acc[0][n], 0, 0, 0);
            acc[1][n] = __builtin_amdgcn_mfma_f32_16x16x32_bf16(a1, bf, acc[1][n], 0, 0, 0);
        }
        __builtin_amdgcn_s_setprio(0);
    }

    // ---- in-register pass 1: tanh-clip + mask + exp-sum (both halves) ----
    float rowsum[2][4];
#pragma unroll
    for (int m = 0; m < 2; m++)
#pragma unroll
        for (int r = 0; r < 4; r++) rowsum[m][r] = 0.f;

    // transform acc in place -> uc (f32 still in acc), accumulate rowsums
#pragma unroll
    for (int m = 0; m < 2; m++) {
        unsigned bits = m ? mw1 : mw0;
#pragma unroll
        for (int n = 0; n < 8; n++)
#pragma unroll
            for (int r = 0; r < 4; r++) {
                float u = acc[m][n][r];
                float e2 = __expf(2.0f * u);
                float tc = 10.0f - 20.0f / (e2 + 1.0f);   // 10*tanh(u)
                bool msk = (bits >> (r * 8 + n)) & 1;
                float uc = msk ? NEG_INF : tc;
                rowsum[m][r] += msk ? 0.0f : __expf(tc);
                acc[m][n][r] = uc;
            }
    }

    // 16-lane row reduce; publish partials to redbuf
#pragma unroll
    for (int m = 0; m < 2; m++)
#pragma unroll
        for (int r = 0; r < 4; r++) {
            float s = rowsum[m][r];
            s += __shfl_xor(s, 1);
            s += __shfl_xor(s, 2);
            s += __shfl_xor(s, 4);
            s += __shfl_xor(s, 8);
            rowsum[m][r] = s;
        }
    if (l15 == 0) {
#pragma unroll
        for (int m = 0; m < 2; m++)
#pragma unroll
            for (int r = 0; r < 4; r++)
                redbuf[(m * 16 + g * 4 + r) * 8 + w] = rowsum[m][r];
    }

    // ---- halves sequential through the single 16-row park ----
#pragma unroll
    for (int m = 0; m < 2; m++) {
        // dump half m (uc already transformed, bf16)
#pragma unroll
        for (int n = 0; n < 8; n++)
#pragma unroll
            for (int r = 0; r < 4; r++)
                park[(g * 4 + r) * RSB + w * 128 + n * 16 + l15] = f2bf(acc[m][n][r]);
        LGKM_BAR();   // park (+redbuf on first iter) visible

        // pass 2: wave w owns park rows 2w, 2w+1; full-row float4 NT stores
#pragma unroll
        for (int rr = 0; rr < 2; rr++) {
            int pr = w * 2 + rr;                           // park row (0..15)
            const float4* rb = reinterpret_cast<const float4*>(&redbuf[(m * 16 + pr) * 8]);
            float4 s0 = rb[0], s1 = rb[1];
            float ssum = ((s0.x + s0.y) + (s0.z + s0.w)) + ((s1.x + s1.y) + (s1.z + s1.w));
            float lser = __logf(fmaxf(ssum, 1e-30f));
            const short* ur2 = park + pr * RSB;
            float* orow = out + ((size_t)b * 1024 + brow + m * 16 + pr) * 1024;
#pragma unroll
            for (int seg = 0; seg < 4; seg++) {
                int col = lane * 4 + seg * 256;
                unsigned lo = *reinterpret_cast<const unsigned*>(&ur2[col]);
                unsigned hi = *reinterpret_cast<const unsigned*>(&ur2[col + 2]);
                f32x4 o = {__uint_as_float(lo << 16) - lser,
                           __uint_as_float(lo & 0xffff0000u) - lser,
                           __uint_as_float(hi << 16) - lser,
                           __uint_as_float(hi & 0xffff0000u) - lser};
                __builtin_nontemporal_store(o, reinterpret_cast<f32x4*>(orow + col));
            }
        }
        if (m == 0) LGKM_BAR();   // all park reads done before m=1 overwrite
    }
}

extern "C" void kernel_launch(void* const* d_in, const int* in_sizes, int n_in,
                              void* d_out, int out_size, void* d_ws, size_t ws_size,
                              hipStream_t stream) {
    const float* q  = (const float*)d_in[0];
    const float* k  = (const float*)d_in[1];
    const float* wq = (const float*)d_in[2];
    const float* wk = (const float*)d_in[3];
    const int* mask = (const int*)d_in[4];
    float* out = (float*)d_out;

    char* ws = (char*)d_ws;
    short* wtq = (short*)ws;                                   // 128KB
    short* wtk = (short*)(ws + 131072);                        // 128KB
    short* Qb  = (short*)(ws + 262144);                        // 32MB
    short* Kb  = (short*)(ws + 262144 + 33554432);             // 32MB
    unsigned* pmask = (unsigned*)(ws + 262144 + 2 * 33554432); // 8.4MB

    wtrans_kernel<<<dim3(8, 8, 2), dim3(32, 8), 0, stream>>>(wq, wk, wtq, wtk);
    proj_kernel<<<dim3(1024, 3), 512, 0, stream>>>(q, k, wtq, wtk, Qb, Kb, mask, pmask);
    attn_kernel<<<dim3(2048), 512, 0, stream>>>(Qb, Kb, pmask, out);
}

// Round 15
// 213.625 us; speedup vs baseline: 1.1491x; 1.1491x over previous
//
#include <hip/hip_runtime.h>
#include <hip/hip_bf16.h>
#include <stdint.h>

#define NEG_INF -100000000.0f

typedef __attribute__((ext_vector_type(8))) short bf16x8;
typedef __attribute__((ext_vector_type(4))) float f32x4;
typedef __attribute__((ext_vector_type(4))) int i32x4;

// lgkm-only barrier: does NOT drain in-flight global stores (unlike __syncthreads,
// which emits s_waitcnt vmcnt(0) before s_barrier). sched_barrier pins LDS ops
// from hoisting above the barrier (rule: inline-asm waitcnt needs a sched fence).
#define LGKM_BAR()                                                \
    do {                                                          \
        asm volatile("s_waitcnt lgkmcnt(0)" ::: "memory");        \
        __builtin_amdgcn_s_barrier();                             \
        __builtin_amdgcn_sched_barrier(0);                        \
    } while (0)

static __device__ __forceinline__ short f2bf(float x) {
    unsigned u = __float_as_uint(x);
    u = u + 0x7FFFu + ((u >> 16) & 1u);
    return (short)(u >> 16);
}

// ---------------- kernel 1: transpose + bf16-convert weights ----------------
__global__ void wtrans_kernel(const float* __restrict__ wq, const float* __restrict__ wk,
                              short* __restrict__ wtq, short* __restrict__ wtk) {
    __shared__ float tile[32][33];
    const float* w = blockIdx.z ? wk : wq;
    short* wt = blockIdx.z ? wtk : wtq;
    float scale = blockIdx.z ? 1.0f : 0.0625f;
    int tx = threadIdx.x, ty = threadIdx.y;
    int c0 = blockIdx.x * 32;
    int k0 = blockIdx.y * 32;
#pragma unroll
    for (int i = 0; i < 4; i++)
        tile[ty + i * 8][tx] = w[(k0 + ty + i * 8) * 256 + c0 + tx];
    __syncthreads();
#pragma unroll
    for (int i = 0; i < 4; i++)
        wt[(c0 + ty + i * 8) * 256 + k0 + tx] = f2bf(tile[tx][ty + i * 8] * scale);
}

// ---------------- kernel 2: projection GEMM + (y==2) mask bit-pack ----------------
// y=0: Q = q @ wq' ; y=1: K = k @ wk  -> fragment-swizzled [b 64][dc 8][row 1024][ks 32]
// y=2: pack mask 268MB -> 8.4MB; word (row,j) bit (i*4+c) = mask[row][j*4+i*128+c].
// Pack blocks dispatch after proj blocks -> streams overlap on the device.
__global__ __launch_bounds__(512, 4)
void proj_kernel(const float* __restrict__ qin, const float* __restrict__ kin,
                 const short* __restrict__ wtq, const short* __restrict__ wtk,
                 short* __restrict__ Qb, short* __restrict__ Kb,
                 const int* __restrict__ mask, unsigned* __restrict__ pmask) {
    if (blockIdx.y == 2) {
        int t = threadIdx.x;
        size_t row = (size_t)blockIdx.x * 64 + (t >> 3);
        int seg8 = t & 7;
        const int* mrow = mask + row * 1024;
#pragma unroll
        for (int jj = 0; jj < 4; jj++) {
            int j = seg8 + jj * 8;
            unsigned v = 0;
#pragma unroll
            for (int i = 0; i < 8; i++) {
                i32x4 x = __builtin_nontemporal_load(
                    reinterpret_cast<const i32x4*>(mrow + j * 4 + i * 128));
                unsigned nib = (unsigned)(x.x | (x.y << 1) | (x.z << 2) | (x.w << 3));
                v |= nib << (i * 4);
            }
            pmask[row * 32 + j] = v;
        }
        return;
    }

    const float* x  = blockIdx.y ? kin : qin;
    const short* wt = blockIdx.y ? wtk : wtq;
    short* outp     = blockIdx.y ? Kb  : Qb;

    __shared__ __align__(16) short sbuf[64 * 296];
    short* xlds = sbuf;                // [64 row][32 k]
    short* wlds = sbuf + 2048;         // [256 c][32 k]

    int t = threadIdx.x;
    int lane = t & 63, w = t >> 6;
    int l15 = lane & 15, g = lane >> 4;
    int rowbase = blockIdx.x * 64;

    f32x4 zero = {0.f, 0.f, 0.f, 0.f};
    f32x4 acc[4][2];
#pragma unroll
    for (int m = 0; m < 4; m++)
#pragma unroll
        for (int n = 0; n < 2; n++) acc[m][n] = zero;

    for (int dc = 0; dc < 8; dc++) {
        __syncthreads();
        {
            int row = t >> 3, seg = t & 7;
            f32x4 v = __builtin_nontemporal_load(
                reinterpret_cast<const f32x4*>(x + (size_t)(rowbase + row) * 256 + dc * 32 + seg * 4));
            short4 bb;
            bb.x = f2bf(v.x); bb.y = f2bf(v.y); bb.z = f2bf(v.z); bb.w = f2bf(v.w);
            *reinterpret_cast<short4*>(&xlds[row * 32 + seg * 4]) = bb;
        }
#pragma unroll
        for (int i = 0; i < 2; i++) {
            int idx = i * 512 + t;
            int c = idx >> 2, seg = idx & 3;
            int4 v = *reinterpret_cast<const int4*>(wt + c * 256 + dc * 32 + seg * 8);
            *reinterpret_cast<int4*>(&wlds[idx * 8]) = v;
        }
        __syncthreads();

        bf16x8 a[4], bfr[2];
#pragma unroll
        for (int m = 0; m < 4; m++)
            a[m] = *reinterpret_cast<const bf16x8*>(&xlds[(m * 16 + l15) * 32 + g * 8]);
#pragma unroll
        for (int n = 0; n < 2; n++) {
            int c = w * 32 + n * 16 + l15;
            bfr[n] = *reinterpret_cast<const bf16x8*>(&wlds[c * 32 + g * 8]);
        }
#pragma unroll
        for (int m = 0; m < 4; m++)
#pragma unroll
            for (int n = 0; n < 2; n++)
                acc[m][n] = __builtin_amdgcn_mfma_f32_16x16x32_bf16(a[m], bfr[n], acc[m][n], 0, 0, 0);
    }

    __syncthreads();
#pragma unroll
    for (int m = 0; m < 4; m++)
#pragma unroll
        for (int n = 0; n < 2; n++) {
            int col = w * 32 + n * 16 + l15;
#pragma unroll
            for (int r = 0; r < 4; r++)
                sbuf[(m * 16 + g * 4 + r) * 296 + col] = f2bf(acc[m][n][r]);
        }
    __syncthreads();

    int b8 = rowbase >> 10;
    int rloc = rowbase & 1023;
#pragma unroll
    for (int o = 0; o < 4; o++) {
        int gu = o * 512 + t;
        int dc = gu >> 8;
        int rem = gu & 255;
        int row = rem >> 2, kseg = rem & 3;
        int4 v = *reinterpret_cast<const int4*>(&sbuf[row * 296 + dc * 32 + kseg * 8]);
        size_t idx = (((size_t)b8 * 8 + dc) * 1024 + rloc + row) * 32 + kseg * 8;
        *reinterpret_cast<int4*>(outp + idx) = v;
    }
}

// ---------------- kernel 3: fused QK^T + tanh-clip + mask + log_softmax ----------------
// R6 epilogue engine (LDS park + row-contiguous float4 NT stores) with lgkm-only
// barriers so NT stores stay in flight across the m=0 -> m=1 transition.
__global__ __launch_bounds__(512, 4)
void attn_kernel(const short* __restrict__ Qs, const short* __restrict__ Ks,
                 const unsigned* __restrict__ pmask, float* __restrict__ out) {
    const int RS = 1028;                               // padded row stride (floats)
    __shared__ __align__(16) float ulds[16 * RS];      // ~64.3KB -> 2 blocks/CU

    int t = threadIdx.x;
    int lane = t & 63, w = t >> 6;
    int l15 = lane & 15, g = lane >> 4;

    int bid = blockIdx.x;
    int wg = (bid & 7) * 256 + (bid >> 3);
    int b = wg >> 5;
    int brow = (wg & 31) * 32;

    // packed-mask prefetch: 2 scalar uints/thread, hidden behind QK^T
    const unsigned* pm = pmask + ((size_t)b * 1024 + brow) * 32;
    unsigned mbits0 = pm[t];
    unsigned mbits1 = pm[512 + t];

    const short* qb = Qs + (size_t)b * 8 * 32768;
    const short* kb = Ks + (size_t)b * 8 * 32768;

    f32x4 zero = {0.f, 0.f, 0.f, 0.f};
    f32x4 acc[2][8];
#pragma unroll
    for (int m = 0; m < 2; m++)
#pragma unroll
        for (int n = 0; n < 8; n++) acc[m][n] = zero;

    for (int dc = 0; dc < 8; dc++) {
        const short* qc = qb + dc * 32768;
        const short* kc = kb + dc * 32768;
        bf16x8 a0 = *reinterpret_cast<const bf16x8*>(qc + (brow + l15) * 32 + g * 8);
        bf16x8 a1 = *reinterpret_cast<const bf16x8*>(qc + (brow + 16 + l15) * 32 + g * 8);
#pragma unroll
        for (int n = 0; n < 8; n++) {
            bf16x8 bf = *reinterpret_cast<const bf16x8*>(kc + (w * 128 + n * 16 + l15) * 32 + g * 8);
            acc[0][n] = __builtin_amdgcn_mfma_f32_16x16x32_bf16(a0, bf, acc[0][n], 0, 0, 0);
            acc[1][n] = __builtin_amdgcn_mfma_f32_16x16x32_bf16(a1, bf, acc[1][n], 0, 0, 0);
        }
    }

    int row = t >> 5;          // 0..15 within half-tile
    int j = t & 31;
    float* urow = ulds + row * RS;

#pragma unroll
    for (int m = 0; m < 2; m++) {
        LGKM_BAR();   // prior half's LDS reads done; prior NT stores stay in flight
        // dump fragments -> LDS U[16][1024] (padded rows)
#pragma unroll
        for (int n = 0; n < 8; n++)
#pragma unroll
            for (int r = 0; r < 4; r++)
                ulds[(g * 4 + r) * RS + w * 128 + n * 16 + l15] = acc[m][n][r];
        LGKM_BAR();

        unsigned bits = m ? mbits1 : mbits0;

        // pass 1: tanh-clip + mask + exp-sum; park uc back in LDS. No global loads.
        float psum = 0.f;
#pragma unroll
        for (int i = 0; i < 8; i++) {
            int col = j * 4 + i * 128;
            float4 u4 = *reinterpret_cast<const float4*>(urow + col);
            float uv[4] = {u4.x, u4.y, u4.z, u4.w};
            float uc[4];
#pragma unroll
            for (int c = 0; c < 4; c++) {
                float e2 = __expf(2.0f * uv[c]);
                float tc = 10.0f - 20.0f / (e2 + 1.0f);   // 10*tanh(u)
                bool msk = (bits >> (i * 4 + c)) & 1;
                uc[c] = msk ? NEG_INF : tc;
                psum += msk ? 0.0f : __expf(tc);
            }
            float4 s = {uc[0], uc[1], uc[2], uc[3]};
            *reinterpret_cast<float4*>(urow + col) = s;
        }
        psum += __shfl_xor(psum, 1);
        psum += __shfl_xor(psum, 2);
        psum += __shfl_xor(psum, 4);
        psum += __shfl_xor(psum, 8);
        psum += __shfl_xor(psum, 16);
        float lse = __logf(fmaxf(psum, 1e-30f));
        float lse0 = __shfl(lse, 0);    // row 2w
        float lse1 = __shfl(lse, 32);   // row 2w+1

        // pass 2: full-wave NT stores; wave w owns rows 2w,2w+1 (wave-local parks,
        // no barrier needed between pass 1 and pass 2)
        float* obase = out + ((size_t)b * 1024 + brow + m * 16) * 1024;
#pragma unroll
        for (int rr = 0; rr < 2; rr++) {
            int r2 = w * 2 + rr;
            float lser = rr ? lse1 : lse0;
            const float* ur2 = ulds + r2 * RS;
            float* orow = obase + (size_t)r2 * 1024;
#pragma unroll
            for (int i2 = 0; i2 < 4; i2++) {
                int col = lane * 4 + i2 * 256;
                float4 u4 = *reinterpret_cast<const float4*>(ur2 + col);
                f32x4 o = {u4.x - lser, u4.y - lser, u4.z - lser, u4.w - lser};
                __builtin_nontemporal_store(o, reinterpret_cast<f32x4*>(orow + col));
            }
        }
    }
}

extern "C" void kernel_launch(void* const* d_in, const int* in_sizes, int n_in,
                              void* d_out, int out_size, void* d_ws, size_t ws_size,
                              hipStream_t stream) {
    const float* q  = (const float*)d_in[0];
    const float* k  = (const float*)d_in[1];
    const float* wq = (const float*)d_in[2];
    const float* wk = (const float*)d_in[3];
    const int* mask = (const int*)d_in[4];
    float* out = (float*)d_out;

    char* ws = (char*)d_ws;
    short* wtq = (short*)ws;                                   // 128KB
    short* wtk = (short*)(ws + 131072);                        // 128KB
    short* Qb  = (short*)(ws + 262144);                        // 32MB
    short* Kb  = (short*)(ws + 262144 + 33554432);             // 32MB
    unsigned* pmask = (unsigned*)(ws + 262144 + 2 * 33554432); // 8.4MB

    wtrans_kernel<<<dim3(8, 8, 2), dim3(32, 8), 0, stream>>>(wq, wk, wtq, wtk);
    proj_kernel<<<dim3(1024, 3), 512, 0, stream>>>(q, k, wtq, wtk, Qb, Kb, mask, pmask);
    attn_kernel<<<dim3(2048), 512, 0, stream>>>(Qb, Kb, pmask, out);
}

// Round 16
// 183.031 us; speedup vs baseline: 1.3412x; 1.1672x over previous
//
#include <hip/hip_runtime.h>
#include <hip/hip_bf16.h>
#include <stdint.h>

#define NEG_INF -100000000.0f

typedef __attribute__((ext_vector_type(8))) short bf16x8;
typedef __attribute__((ext_vector_type(4))) float f32x4;
typedef __attribute__((ext_vector_type(4))) int i32x4;

// lgkm-only barrier: does NOT drain in-flight global stores (unlike __syncthreads,
// which emits s_waitcnt vmcnt(0) before s_barrier). sched_barrier pins LDS ops
// from hoisting above the barrier (rule: inline-asm waitcnt needs a sched fence).
#define LGKM_BAR()                                                \
    do {                                                          \
        asm volatile("s_waitcnt lgkmcnt(0)" ::: "memory");        \
        __builtin_amdgcn_s_barrier();                             \
        __builtin_amdgcn_sched_barrier(0);                        \
    } while (0)

static __device__ __forceinline__ short f2bf(float x) {
    unsigned u = __float_as_uint(x);
    u = u + 0x7FFFu + ((u >> 16) & 1u);
    return (short)(u >> 16);
}
static __device__ __forceinline__ float bfbits2f(unsigned lo16) {
    return __uint_as_float(lo16 << 16);
}

// ---------------- kernel 1: transpose + bf16-convert weights ----------------
__global__ void wtrans_kernel(const float* __restrict__ wq, const float* __restrict__ wk,
                              short* __restrict__ wtq, short* __restrict__ wtk) {
    __shared__ float tile[32][33];
    const float* w = blockIdx.z ? wk : wq;
    short* wt = blockIdx.z ? wtk : wtq;
    float scale = blockIdx.z ? 1.0f : 0.0625f;   // 1/sqrt(256) folded into wq
    int tx = threadIdx.x, ty = threadIdx.y;
    int c0 = blockIdx.x * 32;
    int k0 = blockIdx.y * 32;
#pragma unroll
    for (int i = 0; i < 4; i++)
        tile[ty + i * 8][tx] = w[(k0 + ty + i * 8) * 256 + c0 + tx];
    __syncthreads();
#pragma unroll
    for (int i = 0; i < 4; i++)
        wt[(c0 + ty + i * 8) * 256 + k0 + tx] = f2bf(tile[tx][ty + i * 8] * scale);
}

// ---------------- kernel 2: projection GEMM + (y==2) mask bit-pack ----------------
// y=0: Q = q @ wq' ; y=1: K = k @ wk  -> fragment layout [b][dc 8][row 1024][ks 32] FP8 e4m3
// y=2: pack mask 268MB -> 8.4MB; word (row,j) bit (i*4+c) = mask[row][j*4+i*128+c].
__global__ __launch_bounds__(512, 4)
void proj_kernel(const float* __restrict__ qin, const float* __restrict__ kin,
                 const short* __restrict__ wtq, const short* __restrict__ wtk,
                 unsigned char* __restrict__ Qb, unsigned char* __restrict__ Kb,
                 const int* __restrict__ mask, unsigned* __restrict__ pmask) {
    if (blockIdx.y == 2) {
        int t = threadIdx.x;
        size_t row = (size_t)blockIdx.x * 64 + (t >> 3);
        int seg8 = t & 7;
        const int* mrow = mask + row * 1024;
#pragma unroll
        for (int jj = 0; jj < 4; jj++) {
            int j = seg8 + jj * 8;
            unsigned v = 0;
#pragma unroll
            for (int i = 0; i < 8; i++) {
                i32x4 x = __builtin_nontemporal_load(
                    reinterpret_cast<const i32x4*>(mrow + j * 4 + i * 128));
                unsigned nib = (unsigned)(x.x | (x.y << 1) | (x.z << 2) | (x.w << 3));
                v |= nib << (i * 4);
            }
            pmask[row * 32 + j] = v;
        }
        return;
    }

    const float* x  = blockIdx.y ? kin : qin;
    const short* wt = blockIdx.y ? wtk : wtq;
    unsigned char* outp = blockIdx.y ? Kb : Qb;

    __shared__ __align__(16) short sbuf[64 * 296];
    short* xlds = sbuf;                // [64 row][32 k]
    short* wlds = sbuf + 2048;         // [256 c][32 k]

    int t = threadIdx.x;
    int lane = t & 63, w = t >> 6;
    int l15 = lane & 15, g = lane >> 4;
    int rowbase = blockIdx.x * 64;

    f32x4 zero = {0.f, 0.f, 0.f, 0.f};
    f32x4 acc[4][2];
#pragma unroll
    for (int m = 0; m < 4; m++)
#pragma unroll
        for (int n = 0; n < 2; n++) acc[m][n] = zero;

    for (int dc = 0; dc < 8; dc++) {
        __syncthreads();
        {
            int row = t >> 3, seg = t & 7;
            f32x4 v = __builtin_nontemporal_load(
                reinterpret_cast<const f32x4*>(x + (size_t)(rowbase + row) * 256 + dc * 32 + seg * 4));
            short4 bb;
            bb.x = f2bf(v.x); bb.y = f2bf(v.y); bb.z = f2bf(v.z); bb.w = f2bf(v.w);
            *reinterpret_cast<short4*>(&xlds[row * 32 + seg * 4]) = bb;
        }
#pragma unroll
        for (int i = 0; i < 2; i++) {
            int idx = i * 512 + t;
            int c = idx >> 2, seg = idx & 3;
            int4 v = *reinterpret_cast<const int4*>(wt + c * 256 + dc * 32 + seg * 8);
            *reinterpret_cast<int4*>(&wlds[idx * 8]) = v;
        }
        __syncthreads();

        bf16x8 a[4], bfr[2];
#pragma unroll
        for (int m = 0; m < 4; m++)
            a[m] = *reinterpret_cast<const bf16x8*>(&xlds[(m * 16 + l15) * 32 + g * 8]);
#pragma unroll
        for (int n = 0; n < 2; n++) {
            int c = w * 32 + n * 16 + l15;
            bfr[n] = *reinterpret_cast<const bf16x8*>(&wlds[c * 32 + g * 8]);
        }
#pragma unroll
        for (int m = 0; m < 4; m++)
#pragma unroll
            for (int n = 0; n < 2; n++)
                acc[m][n] = __builtin_amdgcn_mfma_f32_16x16x32_bf16(a[m], bfr[n], acc[m][n], 0, 0, 0);
    }

    // dump C tile to LDS as bf16 [64 row][296] (proven conflict-light layout)
    __syncthreads();
#pragma unroll
    for (int m = 0; m < 4; m++)
#pragma unroll
        for (int n = 0; n < 2; n++) {
            int col = w * 32 + n * 16 + l15;
#pragma unroll
            for (int r = 0; r < 4; r++)
                sbuf[(m * 16 + g * 4 + r) * 296 + col] = f2bf(acc[m][n][r]);
        }
    __syncthreads();

    // write out FP8: read 8 bf16 from park, cvt_pk to 8 fp8, store 8B units.
    // global byte addr = ((b8*8+dc)*1024 + rloc + row)*32 + kseg*8
    int b8 = rowbase >> 10;
    int rloc = rowbase & 1023;
#pragma unroll
    for (int o = 0; o < 4; o++) {
        int gu = o * 512 + t;
        int dc = gu >> 8;
        int rem = gu & 255;
        int row = rem >> 2, kseg = rem & 3;
        int4 v = *reinterpret_cast<const int4*>(&sbuf[row * 296 + dc * 32 + kseg * 8]);
        unsigned uu[4] = {(unsigned)v.x, (unsigned)v.y, (unsigned)v.z, (unsigned)v.w};
        int d0 = 0, d1 = 0;
        d0 = __builtin_amdgcn_cvt_pk_fp8_f32(bfbits2f(uu[0] & 0xffffu), bfbits2f(uu[0] >> 16), d0, 0);
        d0 = __builtin_amdgcn_cvt_pk_fp8_f32(bfbits2f(uu[1] & 0xffffu), bfbits2f(uu[1] >> 16), d0, 1);
        d1 = __builtin_amdgcn_cvt_pk_fp8_f32(bfbits2f(uu[2] & 0xffffu), bfbits2f(uu[2] >> 16), d1, 0);
        d1 = __builtin_amdgcn_cvt_pk_fp8_f32(bfbits2f(uu[3] & 0xffffu), bfbits2f(uu[3] >> 16), d1, 1);
        size_t idx = ((((size_t)b8 * 8 + dc) * 1024 + rloc + row) << 5) + kseg * 8;
        uint2 st = {(unsigned)d0, (unsigned)d1};
        *reinterpret_cast<uint2*>(outp + idx) = st;
    }
}

// ---------------- kernel 3: fused QK^T (fp8) + tanh-clip + mask + log_softmax ----------------
// R8 skeleton verbatim; Q/K fragments are fp8 (half the L2 bytes), MFMA is
// 16x16x32_fp8_fp8 (bf16 rate). Epilogue: LDS park + lgkm-only barriers + NT stores.
__global__ __launch_bounds__(512, 4)
void attn_kernel(const unsigned char* __restrict__ Qs, const unsigned char* __restrict__ Ks,
                 const unsigned* __restrict__ pmask, float* __restrict__ out) {
    const int RS = 1028;                               // padded row stride (floats)
    __shared__ __align__(16) float ulds[16 * RS];      // ~64.3KB -> 2 blocks/CU

    int t = threadIdx.x;
    int lane = t & 63, w = t >> 6;
    int l15 = lane & 15, g = lane >> 4;

    int bid = blockIdx.x;
    int wg = (bid & 7) * 256 + (bid >> 3);   // XCD swizzle: 8 batches/XCD
    int b = wg >> 5;
    int brow = (wg & 31) * 32;

    // packed-mask prefetch: 2 scalar uints/thread, hidden behind QK^T
    const unsigned* pm = pmask + ((size_t)b * 1024 + brow) * 32;
    unsigned mbits0 = pm[t];
    unsigned mbits1 = pm[512 + t];

    const unsigned char* qb = Qs + (size_t)b * 262144;   // 8 dc * 1024 row * 32 B
    const unsigned char* kb = Ks + (size_t)b * 262144;

    f32x4 zero = {0.f, 0.f, 0.f, 0.f};
    f32x4 acc[2][8];
#pragma unroll
    for (int m = 0; m < 2; m++)
#pragma unroll
        for (int n = 0; n < 8; n++) acc[m][n] = zero;

    for (int dc = 0; dc < 8; dc++) {
        const unsigned char* qc = qb + dc * 32768;
        const unsigned char* kc = kb + dc * 32768;
        long long a0 = *reinterpret_cast<const long long*>(qc + (brow + l15) * 32 + g * 8);
        long long a1 = *reinterpret_cast<const long long*>(qc + (brow + 16 + l15) * 32 + g * 8);
#pragma unroll
        for (int n = 0; n < 8; n++) {
            long long bf = *reinterpret_cast<const long long*>(kc + (w * 128 + n * 16 + l15) * 32 + g * 8);
            acc[0][n] = __builtin_amdgcn_mfma_f32_16x16x32_fp8_fp8(a0, bf, acc[0][n], 0, 0, 0);
            acc[1][n] = __builtin_amdgcn_mfma_f32_16x16x32_fp8_fp8(a1, bf, acc[1][n], 0, 0, 0);
        }
    }

    int row = t >> 5;          // 0..15 within half-tile
    int j = t & 31;
    float* urow = ulds + row * RS;

#pragma unroll
    for (int m = 0; m < 2; m++) {
        LGKM_BAR();   // prior half's LDS reads done; prior NT stores stay in flight
        // dump fragments -> LDS U[16][1024] (padded rows)
#pragma unroll
        for (int n = 0; n < 8; n++)
#pragma unroll
            for (int r = 0; r < 4; r++)
                ulds[(g * 4 + r) * RS + w * 128 + n * 16 + l15] = acc[m][n][r];
        LGKM_BAR();

        unsigned bits = m ? mbits1 : mbits0;

        // pass 1: tanh-clip + mask + exp-sum; park uc back in LDS. No global loads.
        float psum = 0.f;
#pragma unroll
        for (int i = 0; i < 8; i++) {
            int col = j * 4 + i * 128;
            float4 u4 = *reinterpret_cast<const float4*>(urow + col);
            float uv[4] = {u4.x, u4.y, u4.z, u4.w};
            float uc[4];
#pragma unroll
            for (int c = 0; c < 4; c++) {
                float e2 = __expf(2.0f * uv[c]);
                float tc = 10.0f - 20.0f / (e2 + 1.0f);   // 10*tanh(u)
                bool msk = (bits >> (i * 4 + c)) & 1;
                uc[c] = msk ? NEG_INF : tc;
                psum += msk ? 0.0f : __expf(tc);
            }
            float4 s = {uc[0], uc[1], uc[2], uc[3]};
            *reinterpret_cast<float4*>(urow + col) = s;
        }
        psum += __shfl_xor(psum, 1);
        psum += __shfl_xor(psum, 2);
        psum += __shfl_xor(psum, 4);
        psum += __shfl_xor(psum, 8);
        psum += __shfl_xor(psum, 16);
        float lse = __logf(fmaxf(psum, 1e-30f));
        float lse0 = __shfl(lse, 0);    // row 2w
        float lse1 = __shfl(lse, 32);   // row 2w+1

        // pass 2: full-wave NT stores; wave w owns rows 2w,2w+1 (wave-local parks)
        float* obase = out + ((size_t)b * 1024 + brow + m * 16) * 1024;
#pragma unroll
        for (int rr = 0; rr < 2; rr++) {
            int r2 = w * 2 + rr;
            float lser = rr ? lse1 : lse0;
            const float* ur2 = ulds + r2 * RS;
            float* orow = obase + (size_t)r2 * 1024;
#pragma unroll
            for (int i2 = 0; i2 < 4; i2++) {
                int col = lane * 4 + i2 * 256;
                float4 u4 = *reinterpret_cast<const float4*>(ur2 + col);
                f32x4 o = {u4.x - lser, u4.y - lser, u4.z - lser, u4.w - lser};
                __builtin_nontemporal_store(o, reinterpret_cast<f32x4*>(orow + col));
            }
        }
    }
}

extern "C" void kernel_launch(void* const* d_in, const int* in_sizes, int n_in,
                              void* d_out, int out_size, void* d_ws, size_t ws_size,
                              hipStream_t stream) {
    const float* q  = (const float*)d_in[0];
    const float* k  = (const float*)d_in[1];
    const float* wq = (const float*)d_in[2];
    const float* wk = (const float*)d_in[3];
    const int* mask = (const int*)d_in[4];
    float* out = (float*)d_out;

    char* ws = (char*)d_ws;
    short* wtq = (short*)ws;                                   // 128KB
    short* wtk = (short*)(ws + 131072);                        // 128KB
    unsigned char* Qb = (unsigned char*)(ws + 262144);         // 16MB (fp8)
    unsigned char* Kb = (unsigned char*)(ws + 262144 + 16777216);  // 16MB (fp8)
    unsigned* pmask = (unsigned*)(ws + 262144 + 2 * 16777216); // 8.4MB

    wtrans_kernel<<<dim3(8, 8, 2), dim3(32, 8), 0, stream>>>(wq, wk, wtq, wtk);
    proj_kernel<<<dim3(1024, 3), 512, 0, stream>>>(q, k, wtq, wtk, Qb, Kb, mask, pmask);
    attn_kernel<<<dim3(2048), 512, 0, stream>>>(Qb, Kb, pmask, out);
}